// Round 3
// baseline (312.188 us; speedup 1.0000x reference)
//
#include <hip/hip_runtime.h>
#include <hip/hip_bf16.h>
#include <math.h>

#define H_ 14
#define W_ 14
#define HW_ 196
#define CIN_ 1024
#define CMID_ 256
#define NCLS_ 27
#define NB_ 16
#define ROIS_ 980
#define M_ 3136
#define FEAT_ 2304

typedef unsigned short u16;
typedef __attribute__((ext_vector_type(8))) short bf16x8;
typedef __attribute__((ext_vector_type(4))) float f32x4;

__device__ __forceinline__ u16 f2bf(float f) {
    __hip_bfloat16 h = __float2bfloat16(f);
    return *reinterpret_cast<u16*>(&h);
}

// ---------------- prep: flat fp32 -> bf16 ----------------
__global__ __launch_bounds__(256) void k_f32_to_bf16(const float* __restrict__ in,
                                                     u16* __restrict__ out) {
    int i = blockIdx.x * 256 + threadIdx.x;
    out[i] = f2bf(in[i]);
}

// ---------------- K0: NCHW fp32 -> NHWC bf16 ----------------
__global__ __launch_bounds__(256) void k_nchw_to_nhwc(const float* __restrict__ in,
                                                      u16* __restrict__ out) {
    int idx = blockIdx.x * 256 + threadIdx.x;   // m*1024 + c
    int m = idx >> 10, c = idx & 1023;
    int b = m / HW_, hw = m - b * HW_;
    out[idx] = f2bf(in[(b * CIN_ + c) * HW_ + hw]);
}

// ---------------- K1/K2: GEMM (A[M,K] * Bw[N,K]^T) + BN epilogue ----------------
// 64x64 tile per block, 4 waves in 2x2, each wave 32x32 via 2x2 mfma_f32_16x16x32_bf16.
template<bool OUT_F32>
__global__ __launch_bounds__(256) void k_gemm_bn(
    const u16* __restrict__ A, const u16* __restrict__ Bw,
    const float* __restrict__ gg, const float* __restrict__ bb,
    const float* __restrict__ mm, const float* __restrict__ vv,
    void* __restrict__ outp, int N, int K)
{
    __shared__ u16 As[64][40];   // +8 bf16 pad (keeps 16B alignment, breaks conflicts)
    __shared__ u16 Bs[64][40];
    const int row0 = blockIdx.y * 64, col0 = blockIdx.x * 64;
    const int t = threadIdx.x;
    const int lr = t >> 2, lk = (t & 3) * 8;       // staging: row, k-offset (8 bf16 = 16B)
    const int wave = t >> 6, lane = t & 63;
    const int wr = (wave >> 1) * 32, wc = (wave & 1) * 32;
    const int fr = lane & 15, fk = (lane >> 4) * 8;
    f32x4 acc[2][2] = {};
    const u16* Aptr = A + (size_t)(row0 + lr) * K + lk;
    const u16* Bptr = Bw + (size_t)(col0 + lr) * K + lk;
    for (int k0 = 0; k0 < K; k0 += 32) {
        *reinterpret_cast<uint4*>(&As[lr][lk]) = *reinterpret_cast<const uint4*>(Aptr + k0);
        *reinterpret_cast<uint4*>(&Bs[lr][lk]) = *reinterpret_cast<const uint4*>(Bptr + k0);
        __syncthreads();
        bf16x8 a0 = *reinterpret_cast<bf16x8*>(&As[wr + fr][fk]);
        bf16x8 a1 = *reinterpret_cast<bf16x8*>(&As[wr + 16 + fr][fk]);
        bf16x8 b0 = *reinterpret_cast<bf16x8*>(&Bs[wc + fr][fk]);
        bf16x8 b1 = *reinterpret_cast<bf16x8*>(&Bs[wc + 16 + fr][fk]);
        acc[0][0] = __builtin_amdgcn_mfma_f32_16x16x32_bf16(a0, b0, acc[0][0], 0, 0, 0);
        acc[0][1] = __builtin_amdgcn_mfma_f32_16x16x32_bf16(a0, b1, acc[0][1], 0, 0, 0);
        acc[1][0] = __builtin_amdgcn_mfma_f32_16x16x32_bf16(a1, b0, acc[1][0], 0, 0, 0);
        acc[1][1] = __builtin_amdgcn_mfma_f32_16x16x32_bf16(a1, b1, acc[1][1], 0, 0, 0);
        __syncthreads();
    }
    #pragma unroll
    for (int ni = 0; ni < 2; ++ni) {
        int col = col0 + wc + ni * 16 + fr;
        float sc = gg[col] * rsqrtf(vv[col] + 1e-5f);
        float bi = bb[col] - mm[col] * sc;
        #pragma unroll
        for (int mi = 0; mi < 2; ++mi) {
            #pragma unroll
            for (int rgi = 0; rgi < 4; ++rgi) {
                int row = row0 + wr + mi * 16 + (lane >> 4) * 4 + rgi;
                float v = acc[mi][ni][rgi] * sc + bi;
                if (OUT_F32) ((float*)outp)[(size_t)row * N + col] = v;
                else         ((u16*)outp)[(size_t)row * N + col] = f2bf(v);
            }
        }
    }
}

// ---------------- K3: fused roi_align + FC ----------------
// one block per roi; thread = channel (256); feats in LDS (CHW order), 4 waves split 27 classes.
__global__ __launch_bounds__(256) void k_roi_fc(
    const float* __restrict__ boxes, const float* __restrict__ fmap,
    const float* __restrict__ wfc, const float* __restrict__ bfc,
    float* __restrict__ out)
{
    __shared__ float feats[FEAT_];
    const int r = blockIdx.x;           // 0..15679
    const int b = r / ROIS_;
    const float* bx = boxes + (size_t)r * 4;
    float x1 = bx[0], y1 = bx[1], x2 = bx[2], y2 = bx[3];
    float rw = fmaxf(x2 - x1, 1.0f), rh = fmaxf(y2 - y1, 1.0f);
    float sx = rw * (1.0f / 3.0f), sy = rh * (1.0f / 3.0f);
    const float OFFS[6] = {0.25f, 0.75f, 1.25f, 1.75f, 2.25f, 2.75f};
    const int c = threadIdx.x;
    const float* fb = fmap + (size_t)b * HW_ * CMID_ + c;
    float pooled[9] = {0.f,0.f,0.f,0.f,0.f,0.f,0.f,0.f,0.f};
    #pragma unroll
    for (int iy = 0; iy < 6; ++iy) {
        float yy = y1 + OFFS[iy] * sy;
        bool vy = (yy >= -1.0f) && (yy <= 14.0f);
        float yc = fmaxf(yy, 0.0f);
        int yl = min((int)yc, 13);
        int yh = min(yl + 1, 13);
        float yv = (yl == 13) ? 13.0f : yc;
        float ly = yv - (float)yl, hy = 1.0f - ly;
        #pragma unroll
        for (int ix = 0; ix < 6; ++ix) {
            float xx = x1 + OFFS[ix] * sx;
            float xc = fmaxf(xx, 0.0f);
            int xl = min((int)xc, 13);
            int xh = min(xl + 1, 13);
            float xv = (xl == 13) ? 13.0f : xc;
            float lx = xv - (float)xl, hx = 1.0f - lx;
            float val = 0.0f;
            if (vy && (xx >= -1.0f) && (xx <= 14.0f)) {
                float f00 = fb[(yl * 14 + xl) * 256];
                float f01 = fb[(yl * 14 + xh) * 256];
                float f10 = fb[(yh * 14 + xl) * 256];
                float f11 = fb[(yh * 14 + xh) * 256];
                val = hy * hx * f00 + hy * lx * f01 + ly * hx * f10 + ly * lx * f11;
            }
            pooled[(iy >> 1) * 3 + (ix >> 1)] += val;
        }
    }
    #pragma unroll
    for (int bin = 0; bin < 9; ++bin) feats[c * 9 + bin] = pooled[bin] * 0.25f;
    __syncthreads();
    const int wave = c >> 6, lane = c & 63;
    const int c0 = wave * 7, c1 = min(c0 + 7, NCLS_);
    for (int cls = c0; cls < c1; ++cls) {
        const float* wrow = wfc + (size_t)cls * FEAT_;
        float s = 0.0f;
        #pragma unroll
        for (int j = 0; j < 36; ++j) {
            int i = lane + j * 64;
            s += feats[i] * wrow[i];
        }
        #pragma unroll
        for (int o = 32; o > 0; o >>= 1) s += __shfl_xor(s, o, 64);
        if (lane == 0) out[(size_t)r * NCLS_ + cls] = s + bfc[cls];
    }
}

extern "C" void kernel_launch(void* const* d_in, const int* in_sizes, int n_in,
                              void* d_out, int out_size, void* d_ws, size_t ws_size,
                              hipStream_t stream) {
    const float* boxes   = (const float*)d_in[0];
    const float* fmap_in = (const float*)d_in[1];
    const float* w1 = (const float*)d_in[2];
    const float* g1 = (const float*)d_in[3];
    const float* b1 = (const float*)d_in[4];
    const float* m1 = (const float*)d_in[5];
    const float* v1 = (const float*)d_in[6];
    const float* w2 = (const float*)d_in[7];
    const float* g2 = (const float*)d_in[8];
    const float* b2 = (const float*)d_in[9];
    const float* m2 = (const float*)d_in[10];
    const float* v2 = (const float*)d_in[11];
    const float* wfc = (const float*)d_in[12];
    const float* bfc = (const float*)d_in[13];

    char* ws = (char*)d_ws;
    u16*   Anhwc = (u16*)ws;                          // 3136*1024*2 = 6,422,528 B
    u16*   h     = (u16*)(ws + 6422528);              // 6,422,528 B
    float* fmapw = (float*)(ws + 2 * 6422528);        // 3136*256*4 = 3,211,264 B
    u16*   w1b   = (u16*)(ws + 2 * 6422528 + 3211264); // 2,097,152 B
    u16*   w2b   = (u16*)(ws + 2 * 6422528 + 3211264 + 2097152); // 524,288 B

    hipLaunchKernelGGL(k_f32_to_bf16, dim3((CIN_ * CIN_) / 256), dim3(256), 0, stream,
                       w1, w1b);
    hipLaunchKernelGGL(k_f32_to_bf16, dim3((CMID_ * CIN_) / 256), dim3(256), 0, stream,
                       w2, w2b);
    hipLaunchKernelGGL(k_nchw_to_nhwc, dim3((M_ * CIN_) / 256), dim3(256), 0, stream,
                       fmap_in, Anhwc);
    hipLaunchKernelGGL((k_gemm_bn<false>), dim3(CIN_ / 64, M_ / 64), dim3(256), 0, stream,
                       Anhwc, w1b, g1, b1, m1, v1, (void*)h, CIN_, CIN_);
    hipLaunchKernelGGL((k_gemm_bn<true>), dim3(CMID_ / 64, M_ / 64), dim3(256), 0, stream,
                       h, w2b, g2, b2, m2, v2, (void*)fmapw, CMID_, CIN_);
    hipLaunchKernelGGL(k_roi_fc, dim3(NB_ * ROIS_), dim3(256), 0, stream,
                       boxes, fmapw, wfc, bfc, (float*)d_out);
}

// Round 4
// 159.314 us; speedup vs baseline: 1.9596x; 1.9596x over previous
//
#include <hip/hip_runtime.h>
#include <hip/hip_bf16.h>
#include <math.h>

#define H_ 14
#define W_ 14
#define HW_ 196
#define CIN_ 1024
#define CMID_ 256
#define NCLS_ 27
#define NB_ 16
#define ROIS_ 980
#define M_ 3136
#define FEAT_ 2304
#define NROI_ (NB_ * ROIS_)   // 15680

typedef unsigned short u16;
typedef __attribute__((ext_vector_type(8))) short bf16x8;
typedef __attribute__((ext_vector_type(4))) float f32x4;

__device__ __forceinline__ float bf2f(u16 u) {
    union { unsigned int i; float f; } x; x.i = ((unsigned int)u) << 16; return x.f;
}
__device__ __forceinline__ u16 f2bf(float f) {
    __hip_bfloat16 h = __float2bfloat16(f);
    return *reinterpret_cast<u16*>(&h);
}

// ---------------- prep: flat fp32 -> bf16 ----------------
__global__ __launch_bounds__(256) void k_f32_to_bf16(const float* __restrict__ in,
                                                     u16* __restrict__ out) {
    int i = blockIdx.x * 256 + threadIdx.x;
    out[i] = f2bf(in[i]);
}

// ---------------- prep: wfc [27][2304 CHW] -> bf16 [32][2304 bin-major], zero-pad ----------------
__global__ __launch_bounds__(256) void k_prep_wfc(const float* __restrict__ wfc,
                                                  u16* __restrict__ wfcb) {
    int idx = blockIdx.x * 256 + threadIdx.x;       // cls*2304 + k, k = bin*256 + c
    int cls = idx / FEAT_;
    int k = idx - cls * FEAT_;
    int c = k & 255, bin = k >> 8;
    float v = (cls < NCLS_) ? wfc[cls * FEAT_ + c * 9 + bin] : 0.0f;
    wfcb[idx] = f2bf(v);
}

// ---------------- K0: NCHW fp32 -> NHWC bf16 ----------------
__global__ __launch_bounds__(256) void k_nchw_to_nhwc(const float* __restrict__ in,
                                                      u16* __restrict__ out) {
    int idx = blockIdx.x * 256 + threadIdx.x;   // m*1024 + c
    int m = idx >> 10, c = idx & 1023;
    int b = m / HW_, hw = m - b * HW_;
    out[idx] = f2bf(in[(b * CIN_ + c) * HW_ + hw]);
}

// ---------------- K1/K2: GEMM (A[M,K] * Bw[N,K]^T) + BN epilogue ----------------
template<bool OUT_F32>
__global__ __launch_bounds__(256) void k_gemm_bn(
    const u16* __restrict__ A, const u16* __restrict__ Bw,
    const float* __restrict__ gg, const float* __restrict__ bb,
    const float* __restrict__ mm, const float* __restrict__ vv,
    void* __restrict__ outp, int N, int K)
{
    __shared__ u16 As[64][40];
    __shared__ u16 Bs[64][40];
    const int row0 = blockIdx.y * 64, col0 = blockIdx.x * 64;
    const int t = threadIdx.x;
    const int lr = t >> 2, lk = (t & 3) * 8;
    const int wave = t >> 6, lane = t & 63;
    const int wr = (wave >> 1) * 32, wc = (wave & 1) * 32;
    const int fr = lane & 15, fk = (lane >> 4) * 8;
    f32x4 acc[2][2] = {};
    const u16* Aptr = A + (size_t)(row0 + lr) * K + lk;
    const u16* Bptr = Bw + (size_t)(col0 + lr) * K + lk;
    for (int k0 = 0; k0 < K; k0 += 32) {
        *reinterpret_cast<uint4*>(&As[lr][lk]) = *reinterpret_cast<const uint4*>(Aptr + k0);
        *reinterpret_cast<uint4*>(&Bs[lr][lk]) = *reinterpret_cast<const uint4*>(Bptr + k0);
        __syncthreads();
        bf16x8 a0 = *reinterpret_cast<bf16x8*>(&As[wr + fr][fk]);
        bf16x8 a1 = *reinterpret_cast<bf16x8*>(&As[wr + 16 + fr][fk]);
        bf16x8 b0 = *reinterpret_cast<bf16x8*>(&Bs[wc + fr][fk]);
        bf16x8 b1 = *reinterpret_cast<bf16x8*>(&Bs[wc + 16 + fr][fk]);
        acc[0][0] = __builtin_amdgcn_mfma_f32_16x16x32_bf16(a0, b0, acc[0][0], 0, 0, 0);
        acc[0][1] = __builtin_amdgcn_mfma_f32_16x16x32_bf16(a0, b1, acc[0][1], 0, 0, 0);
        acc[1][0] = __builtin_amdgcn_mfma_f32_16x16x32_bf16(a1, b0, acc[1][0], 0, 0, 0);
        acc[1][1] = __builtin_amdgcn_mfma_f32_16x16x32_bf16(a1, b1, acc[1][1], 0, 0, 0);
        __syncthreads();
    }
    #pragma unroll
    for (int ni = 0; ni < 2; ++ni) {
        int col = col0 + wc + ni * 16 + fr;
        float sc = gg[col] * rsqrtf(vv[col] + 1e-5f);
        float bi = bb[col] - mm[col] * sc;
        #pragma unroll
        for (int mi = 0; mi < 2; ++mi) {
            #pragma unroll
            for (int rgi = 0; rgi < 4; ++rgi) {
                int row = row0 + wr + mi * 16 + (lane >> 4) * 4 + rgi;
                float v = acc[mi][ni][rgi] * sc + bi;
                if (OUT_F32) ((float*)outp)[(size_t)row * N + col] = v;
                else         ((u16*)outp)[(size_t)row * N + col] = f2bf(v);
            }
        }
    }
}

// ---------------- K3a: roi_align -> feats bf16 [NROI][9*256], bin-major ----------------
// one block per roi; thread = channel. Inputs guarantee samples in-bounds (x1,y1>=0,
// x2,y2<=14) so the torchvision validity check is statically true and dropped.
__global__ __launch_bounds__(256) void k_roi_feats(
    const float* __restrict__ boxes, const u16* __restrict__ fmap,
    u16* __restrict__ feats)
{
    const int r = blockIdx.x;
    const int b = r / ROIS_;
    const float* bx = boxes + (size_t)r * 4;
    float x1 = bx[0], y1 = bx[1];
    float rw = fmaxf(bx[2] - x1, 1.0f), rh = fmaxf(bx[3] - y1, 1.0f);
    float sx = rw * (1.0f / 3.0f), sy = rh * (1.0f / 3.0f);
    const float OFFS[6] = {0.25f, 0.75f, 1.25f, 1.75f, 2.25f, 2.75f};
    const int c = threadIdx.x;
    const u16* fb = fmap + (size_t)b * HW_ * CMID_ + c;

    int xls[6], xhs[6]; float lxs[6], hxs[6];
    #pragma unroll
    for (int i = 0; i < 6; ++i) {
        float xx = x1 + OFFS[i] * sx;
        float xc = fmaxf(xx, 0.0f);
        int xl = min((int)xc, 13);
        int xh = min(xl + 1, 13);
        float xv = (xl == 13) ? 13.0f : xc;
        lxs[i] = xv - (float)xl; hxs[i] = 1.0f - lxs[i];
        xls[i] = xl << 8; xhs[i] = xh << 8;
    }
    float pooled[9] = {0.f,0.f,0.f,0.f,0.f,0.f,0.f,0.f,0.f};
    #pragma unroll
    for (int iy = 0; iy < 6; ++iy) {
        float yy = y1 + OFFS[iy] * sy;
        float yc = fmaxf(yy, 0.0f);
        int yl = min((int)yc, 13);
        int yh = min(yl + 1, 13);
        float yv = (yl == 13) ? 13.0f : yc;
        float ly = yv - (float)yl, hy = 1.0f - ly;
        const int ylo = (yl * 14) << 8, yho = (yh * 14) << 8;
        #pragma unroll
        for (int ix = 0; ix < 6; ++ix) {
            float f00 = bf2f(fb[ylo + xls[ix]]);
            float f01 = bf2f(fb[ylo + xhs[ix]]);
            float f10 = bf2f(fb[yho + xls[ix]]);
            float f11 = bf2f(fb[yho + xhs[ix]]);
            float t0 = fmaf(lxs[ix], f01, hxs[ix] * f00);
            float t1 = fmaf(lxs[ix], f11, hxs[ix] * f10);
            pooled[(iy >> 1) * 3 + (ix >> 1)] += fmaf(hy, t0, ly * t1);
        }
    }
    u16* fo = feats + (size_t)r * FEAT_ + c;
    #pragma unroll
    for (int bin = 0; bin < 9; ++bin) fo[bin * 256] = f2bf(pooled[bin] * 0.25f);
}

// ---------------- K3b: FC GEMM  out[NROI,27] = feats[NROI,2304] * wfcb[32,2304]^T + bfc ----
// 64(M)x32(N) tile, 4 waves stacked on M, BK=64, reg-prefetch pipeline.
__global__ __launch_bounds__(256) void k_fc(
    const u16* __restrict__ feats, const u16* __restrict__ wfcb,
    const float* __restrict__ bfc, float* __restrict__ out)
{
    __shared__ u16 As[64][72];
    __shared__ u16 Bs[32][72];
    const int row0 = blockIdx.x * 64;
    const int t = threadIdx.x, wave = t >> 6, lane = t & 63;
    const int fr = lane & 15, fk = (lane >> 4) * 8;
    const int ar = t >> 2, ak = (t & 3) * 8;     // A: 4 thr/row, 2 x uint4 (ak, ak+32)
    const int br = t >> 3, bk = (t & 7) * 8;     // B: 8 thr/row, 1 x uint4
    f32x4 acc[2] = {};
    const u16* Ap = feats + (size_t)(row0 + ar) * FEAT_ + ak;
    const u16* Bp = wfcb + (size_t)br * FEAT_ + bk;
    uint4 a0n = *reinterpret_cast<const uint4*>(Ap);
    uint4 a1n = *reinterpret_cast<const uint4*>(Ap + 32);
    uint4 b0n = *reinterpret_cast<const uint4*>(Bp);
    for (int k0 = 0; k0 < FEAT_; k0 += 64) {
        *reinterpret_cast<uint4*>(&As[ar][ak]) = a0n;
        *reinterpret_cast<uint4*>(&As[ar][ak + 32]) = a1n;
        *reinterpret_cast<uint4*>(&Bs[br][bk]) = b0n;
        __syncthreads();
        if (k0 + 64 < FEAT_) {
            a0n = *reinterpret_cast<const uint4*>(Ap + k0 + 64);
            a1n = *reinterpret_cast<const uint4*>(Ap + k0 + 96);
            b0n = *reinterpret_cast<const uint4*>(Bp + k0 + 64);
        }
        #pragma unroll
        for (int kk = 0; kk < 64; kk += 32) {
            bf16x8 a  = *reinterpret_cast<bf16x8*>(&As[wave * 16 + fr][fk + kk]);
            bf16x8 b0 = *reinterpret_cast<bf16x8*>(&Bs[fr][fk + kk]);
            bf16x8 b1 = *reinterpret_cast<bf16x8*>(&Bs[16 + fr][fk + kk]);
            acc[0] = __builtin_amdgcn_mfma_f32_16x16x32_bf16(a, b0, acc[0], 0, 0, 0);
            acc[1] = __builtin_amdgcn_mfma_f32_16x16x32_bf16(a, b1, acc[1], 0, 0, 0);
        }
        __syncthreads();
    }
    #pragma unroll
    for (int ni = 0; ni < 2; ++ni) {
        int col = ni * 16 + fr;
        if (col < NCLS_) {
            float bi = bfc[col];
            #pragma unroll
            for (int rgi = 0; rgi < 4; ++rgi) {
                int row = row0 + wave * 16 + (lane >> 4) * 4 + rgi;
                out[(size_t)row * NCLS_ + col] = acc[ni][rgi] + bi;
            }
        }
    }
}

extern "C" void kernel_launch(void* const* d_in, const int* in_sizes, int n_in,
                              void* d_out, int out_size, void* d_ws, size_t ws_size,
                              hipStream_t stream) {
    const float* boxes   = (const float*)d_in[0];
    const float* fmap_in = (const float*)d_in[1];
    const float* w1 = (const float*)d_in[2];
    const float* g1 = (const float*)d_in[3];
    const float* b1 = (const float*)d_in[4];
    const float* m1 = (const float*)d_in[5];
    const float* v1 = (const float*)d_in[6];
    const float* w2 = (const float*)d_in[7];
    const float* g2 = (const float*)d_in[8];
    const float* b2 = (const float*)d_in[9];
    const float* m2 = (const float*)d_in[10];
    const float* v2 = (const float*)d_in[11];
    const float* wfc = (const float*)d_in[12];
    const float* bfc = (const float*)d_in[13];

    char* ws = (char*)d_ws;
    u16* Anhwc = (u16*)(ws + 0);                     //  6,422,528 B
    u16* h     = (u16*)(ws + 6422528);               //  6,422,528 B
    u16* fmapw = (u16*)(ws + 12845056);              //  1,605,632 B (bf16 now)
    u16* w1b   = (u16*)(ws + 14450688);              //  2,097,152 B
    u16* w2b   = (u16*)(ws + 16547840);              //    524,288 B
    u16* wfcb  = (u16*)(ws + 17072128);              //    147,456 B
    u16* feats = (u16*)(ws + 17219584);              // 72,253,440 B  (total ~85.3 MB)

    hipLaunchKernelGGL(k_f32_to_bf16, dim3((CIN_ * CIN_) / 256), dim3(256), 0, stream,
                       w1, w1b);
    hipLaunchKernelGGL(k_f32_to_bf16, dim3((CMID_ * CIN_) / 256), dim3(256), 0, stream,
                       w2, w2b);
    hipLaunchKernelGGL(k_prep_wfc, dim3((32 * FEAT_) / 256), dim3(256), 0, stream,
                       wfc, wfcb);
    hipLaunchKernelGGL(k_nchw_to_nhwc, dim3((M_ * CIN_) / 256), dim3(256), 0, stream,
                       fmap_in, Anhwc);
    hipLaunchKernelGGL((k_gemm_bn<false>), dim3(CIN_ / 64, M_ / 64), dim3(256), 0, stream,
                       Anhwc, w1b, g1, b1, m1, v1, (void*)h, CIN_, CIN_);
    hipLaunchKernelGGL((k_gemm_bn<false>), dim3(CMID_ / 64, M_ / 64), dim3(256), 0, stream,
                       h, w2b, g2, b2, m2, v2, (void*)fmapw, CMID_, CIN_);
    hipLaunchKernelGGL(k_roi_feats, dim3(NROI_), dim3(256), 0, stream,
                       boxes, fmapw, feats);
    hipLaunchKernelGGL(k_fc, dim3(NROI_ / 64), dim3(256), 0, stream,
                       feats, wfcb, bfc, (float*)d_out);
}